// Round 5
// baseline (751.338 us; speedup 1.0000x reference)
//
#include <hip/hip_runtime.h>

typedef unsigned int uint;
typedef unsigned short ushort;
typedef __attribute__((ext_vector_type(8))) short short8;
typedef __attribute__((ext_vector_type(4))) float floatx4;
typedef __attribute__((ext_vector_type(4))) uint uintx4;

#define NPAIR 36
#define NPQ   666
#define NPQP  672
#define NCHUNK 21
#define NH    64
#define NB    4096
#define NHALF 2048
#define NRBF  50

// ---- compile-time LUT: unordered pair-pair (P<=Q) enumeration ----
struct Luts { short P[NPQP]; short Q[NPQP]; };
static constexpr Luts make_luts() {
  Luts L{};
  int t = 0;
  for (int p = 0; p < NPAIR; ++p)
    for (int q = p; q < NPAIR; ++q) { L.P[t] = (short)p; L.Q[t] = (short)q; ++t; }
  for (; t < NPQP; ++t) { L.P[t] = 0; L.Q[t] = 0; }
  return L;
}
static constexpr Luts LUT = make_luts();

__device__ __forceinline__ float sel4(bool b0, bool b1, float v0, float v1, float v2, float v3) {
  float a = b0 ? v1 : v0;
  float b = b0 ? v3 : v2;
  return b1 ? b : a;
}

// =====================================================================
// prep: per-b pair geometry, RBF smearing, feat (f32), G (f32, slot-permuted)
// Processes a HALF batch: global b = b0 + blockIdx.x, local index blockIdx.x.
// feat layout: [bl][k=64][P=36] f32.  G layout: [bl][672] f32, slot order:
//   slot(c*32 + g*8 + j) holds G for pq = c*32 + j*4 + g
// =====================================================================
__global__ __launch_bounds__(256) void prep_kernel(
    const float* __restrict__ x, const float* __restrict__ means,
    const float* __restrict__ betas, const float* __restrict__ as_w,
    const float* __restrict__ as_b, float* __restrict__ feat_ws,
    float* __restrict__ g_ws, int b0)
{
  __shared__ float s_x[27];
  __shared__ float s_asw[NH * NRBF];
  __shared__ float s_asb[NH];
  __shared__ float s_means[NRBF], s_betas[NRBF];
  __shared__ float s_dn[NPAIR][3];
  __shared__ float s_ed2[NPAIR], s_cut[NPAIR];
  __shared__ float s_rbf[NPAIR * NRBF];

  const int bl = blockIdx.x;            // local (within half)
  const int b  = b0 + bl;               // global
  const int tid = threadIdx.x;
  for (int i = tid; i < 27; i += 256) s_x[i] = x[b * 27 + i];
  for (int i = tid; i < NH * NRBF; i += 256) s_asw[i] = as_w[i];
  for (int i = tid; i < NH; i += 256) s_asb[i] = as_b[i];
  for (int i = tid; i < NRBF; i += 256) { s_means[i] = means[i]; s_betas[i] = betas[i]; }
  __syncthreads();

  if (tid < NPAIR) {
    int a = 0, rem = tid;
    while (rem >= 8 - a) { rem -= 8 - a; ++a; }
    int e = a + 1 + rem;                       // a < e
    float dx = s_x[a * 3 + 0] - s_x[e * 3 + 0];
    float dy = s_x[a * 3 + 1] - s_x[e * 3 + 1];
    float dz = s_x[a * 3 + 2] - s_x[e * 3 + 2];
    float d2 = dx * dx + dy * dy + dz * dz;
    float inv = 1.0f / (d2 + 1e-6f);
    s_dn[tid][0] = dx * inv; s_dn[tid][1] = dy * inv; s_dn[tid][2] = dz * inv;
    s_ed2[tid] = expf(-d2);                    // ALPHA = 1, CUTOFF_LOWER = 0
    s_cut[tid] = (d2 < 5.0f) ? 0.5f * (cosf(d2 * 0.6283185307179586f) + 1.0f) : 0.0f;
  }
  __syncthreads();

  for (int i = tid; i < NPAIR * NRBF; i += 256) {
    int p = i / NRBF, r = i - p * NRBF;
    float dv = s_ed2[p] - s_means[r];
    s_rbf[i] = s_cut[p] * expf(-s_betas[r] * dv * dv);
  }
  __syncthreads();

  for (int i = tid; i < NH * NPAIR; i += 256) {
    int k = i / NPAIR, p = i - k * NPAIR;
    float sum = s_asb[k];
    #pragma unroll 10
    for (int r = 0; r < NRBF; ++r) sum += s_rbf[p * NRBF + r] * s_asw[k * NRBF + r];
    feat_ws[((size_t)bl * NH + k) * NPAIR + p] = sum;
  }

  for (int t = tid; t < NPQP; t += 256) {
    float val = 0.0f;
    if (t < NPQ) {
      int p = 0, rem = t;
      while (rem >= NPAIR - p) { rem -= NPAIR - p; ++p; }
      int q = p + rem;
      val = s_dn[p][0] * s_dn[q][0] + s_dn[p][1] * s_dn[q][1] + s_dn[p][2] * s_dn[q][2];
    }
    int pos = (t & ~31) | ((t & 3) << 3) | ((t >> 2) & 7);   // slot permutation
    g_ws[(size_t)bl * NPQP + pos] = val;
  }
}

// =====================================================================
// fold: W2fold[pq][k][o] = sign-folded sum of 4 (or 8) W entries, split into
// hi/lo bf16 (bf16x3 scheme), written in MFMA B-fragment order:
//   frag = ((k*21+c)*4 + ot)*64 + (g*16 + (o&15));  pq = c*32 + j*4 + g
//   w2s[frag*16 + j]     = hi,  w2s[frag*16 + 8 + j] = lo
// =====================================================================
__global__ __launch_bounds__(256) void fold_kernel(
    const float* __restrict__ W, ushort* __restrict__ w2s)
{
  const int t  = blockIdx.x;              // 0..671 (pq, padded)
  const int kk = threadIdx.x >> 6;
  const int k  = blockIdx.y * 4 + kk;     // 0..63
  const int o  = threadIdx.x & 63;

  float val = 0.0f;
  if (t < NPQ) {
    int p = 0, rem = t;
    while (rem >= NPAIR - p) { rem -= NPAIR - p; ++p; }
    int q = p + rem;
    int a = 0, rp = p;
    while (rp >= 8 - a) { rp -= 8 - a; ++a; }
    int e = a + 1 + rp;
    int d = 0, rq = q;
    while (rq >= 8 - d) { rq -= 8 - d; ++d; }
    int f = d + 1 + rq;
    int p1 = a * 9 + e, p2 = e * 9 + a;
    int q1 = d * 9 + f, q2 = f * 9 + d;
    const size_t ko = (size_t)k * 64 + o;
    const float* Wb = W;
    #define WAT(pp, qq) Wb[((size_t)((pp) * 81 + (qq))) * 4096 + ko]
    val = WAT(p1, q1) - WAT(p2, q1) - WAT(p1, q2) + WAT(p2, q2);
    if (p != q) val += WAT(q1, p1) - WAT(q2, p1) - WAT(q1, p2) + WAT(q2, p2);
    #undef WAT
  }
  // trunc-split: hi = truncate-to-bf16(val), lo = trunc-bf16(val - hi)
  uint ub = __float_as_uint(val);
  uint hi_bits = ub & 0xffff0000u;
  float lo = val - __uint_as_float(hi_bits);
  uint lo_bits = __float_as_uint(lo);

  const int c = t >> 5, g = t & 3, j = (t >> 2) & 7;
  const size_t frag =
      (((size_t)(k * NCHUNK + c) * 4 + (o >> 4)) * 64) + (g * 16 + (o & 15));
  w2s[frag * 16 + j]     = (ushort)(hi_bits >> 16);
  w2s[frag * 16 + 8 + j] = (ushort)(lo_bits >> 16);
}

// =====================================================================
// main: out_H[b][o] += sum over pq,k of G*fP*fQ*W2fold via bf16x3 MFMA
// (a_hi*b_hi + a_hi*b_lo + a_lo*b_hi). Wave owns 32 rows x 64 o.
// Processes a half batch (2048 rows local, global = b0 + local).
// A-fragments formed entirely in registers; packing is pure bit ops
// (no inline asm). Split-K=32 via f32 atomics into global outH.
// =====================================================================
__global__ __launch_bounds__(256, 2) void main_kernel(
    const float* __restrict__ feat, const float* __restrict__ G,
    const ushort* __restrict__ w2s, float* __restrict__ outH, int b0)
{
  const int tid  = threadIdx.x;
  const int lane = tid & 63;
  const int wv   = tid >> 6;            // wave id: row group
  const int g    = lane >> 4;           // 0..3
  const bool gb0 = (g & 1) != 0;
  const bool gb1 = (g & 2) != 0;
  const int r16  = lane & 15;
  const int s    = blockIdx.x;          // k-split: k in {2s, 2s+1}
  const int rowbase = blockIdx.y * 128 + wv * 32 + r16;  // local m=0 A-row

  floatx4 acc[2][4];
  #pragma unroll
  for (int m = 0; m < 2; ++m)
    #pragma unroll
    for (int ot = 0; ot < 4; ++ot) acc[m][ot] = (floatx4){0.f, 0.f, 0.f, 0.f};

  for (int kk = 0; kk < 2; ++kk) {
    const int k = s * 2 + kk;
    // feat for this lane's two rows into registers (static indexing only)
    float f[2][NPAIR];
    #pragma unroll
    for (int m = 0; m < 2; ++m) {
      const floatx4* fp =
          (const floatx4*)(feat + ((size_t)(rowbase + m * 16) * NH + k) * NPAIR);
      #pragma unroll
      for (int i = 0; i < 9; ++i) {
        floatx4 v = fp[i];
        f[m][i * 4 + 0] = v.x; f[m][i * 4 + 1] = v.y;
        f[m][i * 4 + 2] = v.z; f[m][i * 4 + 3] = v.w;
      }
    }

    #pragma unroll
    for (int c = 0; c < NCHUNK; ++c) {
      // B-fragments: pre-swizzled hi/lo, one dwordx4 each per o-tile
      uintx4 bh[4], bl[4];
      #pragma unroll
      for (int ot = 0; ot < 4; ++ot) {
        const uintx4* bp = (const uintx4*)(w2s +
            (((size_t)(k * NCHUNK + c) * 4 + ot) * 64 + lane) * 16);
        bh[ot] = bp[0];
        bl[ot] = bp[1];
      }

      short8 afH[2], afL[2];
      #pragma unroll
      for (int m = 0; m < 2; ++m) {
        const float* gp = G + (size_t)(rowbase + m * 16) * NPQP + c * 32 + g * 8;
        floatx4 g0 = *(const floatx4*)gp;
        floatx4 g1 = *(const floatx4*)(gp + 4);
        float gv[8] = {g0.x, g0.y, g0.z, g0.w, g1.x, g1.y, g1.z, g1.w};
        float av[8];
        #pragma unroll
        for (int j = 0; j < 8; ++j) {
          const int base = c * 32 + j * 4;     // pq = base + g
          float fp_ = sel4(gb0, gb1,
                           f[m][LUT.P[base + 0]], f[m][LUT.P[base + 1]],
                           f[m][LUT.P[base + 2]], f[m][LUT.P[base + 3]]);
          float fq_ = sel4(gb0, gb1,
                           f[m][LUT.Q[base + 0]], f[m][LUT.Q[base + 1]],
                           f[m][LUT.Q[base + 2]], f[m][LUT.Q[base + 3]]);
          av[j] = gv[j] * fp_ * fq_;
        }
        // pure-bit truncation split into packed bf16 pairs
        union { short8 s8; uint u[4]; } ph, pl;
        #pragma unroll
        for (int i = 0; i < 4; ++i) {
          uint bb0 = __float_as_uint(av[2 * i]);
          uint bb1 = __float_as_uint(av[2 * i + 1]);
          uint h0 = bb0 & 0xffff0000u;
          uint h1 = bb1 & 0xffff0000u;
          ph.u[i] = h1 | (h0 >> 16);
          float l0 = av[2 * i]     - __uint_as_float(h0);
          float l1 = av[2 * i + 1] - __uint_as_float(h1);
          pl.u[i] = (__float_as_uint(l1) & 0xffff0000u) | (__float_as_uint(l0) >> 16);
        }
        afH[m] = ph.s8;
        afL[m] = pl.s8;
      }

      #pragma unroll
      for (int m = 0; m < 2; ++m)
        #pragma unroll
        for (int ot = 0; ot < 4; ++ot) {
          union { uintx4 u; short8 s; } ch, cl;
          ch.u = bh[ot]; cl.u = bl[ot];
          acc[m][ot] = __builtin_amdgcn_mfma_f32_16x16x32_bf16(
              afH[m], ch.s, acc[m][ot], 0, 0, 0);
          acc[m][ot] = __builtin_amdgcn_mfma_f32_16x16x32_bf16(
              afH[m], cl.s, acc[m][ot], 0, 0, 0);
          acc[m][ot] = __builtin_amdgcn_mfma_f32_16x16x32_bf16(
              afL[m], ch.s, acc[m][ot], 0, 0, 0);
        }
    }
  }

  // epilogue: D layout col = lane&15, row = (lane>>4)*4 + reg
  #pragma unroll
  for (int m = 0; m < 2; ++m)
    #pragma unroll
    for (int ot = 0; ot < 4; ++ot)
      #pragma unroll
      for (int rr = 0; rr < 4; ++rr) {
        int row = b0 + blockIdx.y * 128 + wv * 32 + m * 16 + g * 4 + rr;
        int o = ot * 16 + r16;
        unsafeAtomicAdd(&outH[(size_t)row * NH + o], acc[m][ot][rr]);
      }
}

// =====================================================================
// reduce: out[b] = sum_o silu(out_H[b][o]) * fc_w[o] + fc_b
// =====================================================================
__global__ __launch_bounds__(256) void reduce_kernel(
    const float* __restrict__ outH, const float* __restrict__ fc_w,
    const float* __restrict__ fc_b, float* __restrict__ out)
{
  const int b = blockIdx.x * 4 + (threadIdx.x >> 6);
  const int o = threadIdx.x & 63;
  float h = outH[(size_t)b * NH + o];
  float sg = h / (1.0f + expf(-h));
  float v = sg * fc_w[o];
  #pragma unroll
  for (int off = 32; off > 0; off >>= 1) v += __shfl_xor(v, off, 64);
  if (o == 0) out[b] = v + fc_b[0];
}

// =====================================================================
extern "C" void kernel_launch(void* const* d_in, const int* in_sizes, int n_in,
                              void* d_out, int out_size, void* d_ws, size_t ws_size,
                              hipStream_t stream)
{
  const float* x     = (const float*)d_in[0];
  const float* W     = (const float*)d_in[1];
  const float* means = (const float*)d_in[2];
  const float* betas = (const float*)d_in[3];
  const float* as_w  = (const float*)d_in[4];
  const float* as_b  = (const float*)d_in[5];
  const float* fc_w  = (const float*)d_in[6];
  const float* fc_b  = (const float*)d_in[7];

  char* ws = (char*)d_ws;
  // layout (36.4 MB total, reused across the two half-batches):
  //   w2s  bf16 hi/lo : [0,        11010048)
  //   feat f32 (half) : [11010048, 29884416)   2048*64*36*4
  //   G    f32 (half) : [29884416, 35389440)   2048*672*4
  //   outH f32 (full) : [35389440, 36438016)   4096*64*4
  ushort* w2s = (ushort*)(ws + 0);
  float* feat = (float*)(ws + 11010048);
  float* g_ws = (float*)(ws + 29884416);
  float* outH = (float*)(ws + 35389440);

  hipMemsetAsync(outH, 0, (size_t)NB * NH * sizeof(float), stream);
  hipLaunchKernelGGL(fold_kernel, dim3(NPQP, 16), dim3(256), 0, stream, W, w2s);
  // half 0
  hipLaunchKernelGGL(prep_kernel, dim3(NHALF), dim3(256), 0, stream,
                     x, means, betas, as_w, as_b, feat, g_ws, 0);
  hipLaunchKernelGGL(main_kernel, dim3(32, 16), dim3(256), 0, stream,
                     feat, g_ws, w2s, outH, 0);
  // half 1 (reuses feat/G buffers; stream order guarantees main0 finished reads)
  hipLaunchKernelGGL(prep_kernel, dim3(NHALF), dim3(256), 0, stream,
                     x, means, betas, as_w, as_b, feat, g_ws, NHALF);
  hipLaunchKernelGGL(main_kernel, dim3(32, 16), dim3(256), 0, stream,
                     feat, g_ws, w2s, outH, NHALF);
  hipLaunchKernelGGL(reduce_kernel, dim3(NB / 4), dim3(256), 0, stream,
                     outH, fc_w, fc_b, (float*)d_out);
}